// Round 14
// baseline (330.431 us; speedup 1.0000x reference)
//
#include <hip/hip_runtime.h>

#define BB 8
#define LL 512
#define HH 8
#define BIGV (1e9f)

typedef unsigned short u16;
typedef __attribute__((ext_vector_type(8))) short bf16x8;
typedef __attribute__((ext_vector_type(4))) short s16x4;
typedef __attribute__((ext_vector_type(4))) float f32x4;

#define MFMA(a,b,c) __builtin_amdgcn_mfma_f32_16x16x32_bf16(a,b,c,0,0,0)

__device__ __forceinline__ u16 f2b(float f){
  unsigned u = __float_as_uint(f);
  u = (u + 0x7fffu + ((u>>16)&1u)) >> 16;
  return (u16)u;
}
__device__ __forceinline__ float b2f(u16 s){ return __uint_as_float(((unsigned)s)<<16); }
__device__ __forceinline__ bf16x8 ldb8(const u16* p){ return *(const bf16x8*)p; }

__device__ __forceinline__ float g16_sum(float v){
  v += __shfl_xor(v,1,64); v += __shfl_xor(v,2,64);
  v += __shfl_xor(v,4,64); v += __shfl_xor(v,8,64);
  return v;
}

// ---- tables: T4t[c][b][a], Tt2[c][a][b], Gt[a][j], Gt2[j][a] ----
__global__ void kp_prep(const float* __restrict__ T, const float* __restrict__ gw,
                        u16* __restrict__ T4t, u16* __restrict__ Tt2,
                        u16* __restrict__ Gt, u16* __restrict__ Gt2){
  int idx = blockIdx.x*256 + threadIdx.x;   // < 32768
  { int c=idx>>12, b=(idx>>6)&63, a=idx&63; T4t[idx] = f2b(T[(a*64+b)*8+c]); }
  { int c=idx>>12, a=(idx>>6)&63, b=idx&63; Tt2[idx] = f2b(T[(a*64+b)*8+c]); }
  if(idx < 4096){
    int a=idx>>6, j=idx&63;
    Gt[idx]  = f2b(gw[j*64+a]);   // Gt[a][j]
    Gt2[idx] = f2b(gw[idx]);      // Gt2[j][a]
  }
}

// ---- kCA: fused [new_qz] + [row softmax in-register] + [P2/Mg MFMA] ----
__global__ __launch_bounds__(256) void kCA(const float* __restrict__ x, const int* __restrict__ mask,
      const u16* __restrict__ miP, const u16* __restrict__ mjP, const float* __restrict__ MgF_in,
      float* __restrict__ unary, float* __restrict__ mf,
      const u16* __restrict__ Gt2, const u16* __restrict__ Gt,
      u16* __restrict__ qzb, float* __restrict__ MgF_out, float* __restrict__ out, int mode){
  __shared__ u16 qlds[16*72];
  __shared__ u16 P2s[16*72];
  __shared__ float red2[16*4];
  int bid = blockIdx.x; int z = bid & 7, itile = bid >> 3;   // z-affine for XCD L2
  int t = threadIdx.x, lane = t&63, w = t>>6, l15 = lane&15, lhi = lane>>4;
  int rbase = z*LL + itile*16;
  {
    int row16 = t>>4, c4 = t&15;
    int rg = rbase + row16;
    float v[4]; float mk;
    if(mode == 0){
      mk = (mask[rg] != 0) ? 1.f : 0.f;
      if(c4 == 0) mf[rg] = mk;
      int pos = rg & (LL-1);
      #pragma unroll
      for(int k=0;k<4;k++){
        int d = c4*4 + k;
        float div = __expf(-(float)(d & ~1) * 0.14391156962f);  // ln(10000)/64
        float arg = (float)pos * div;
        float pe = (d & 1) ? cosf(arg) : sinf(arg);
        v[k] = (x[(size_t)rg*64 + d] + pe) * mk;
      }
      *(f32x4*)&unary[(size_t)rg*64 + c4*4] = (f32x4){v[0],v[1],v[2],v[3]};
    } else {
      mk = mf[rg];
      f32x4 acc = *(const f32x4*)&MgF_in[(size_t)rg*64 + c4*4];
      #pragma unroll
      for(int c=0;c<8;c++){
        s16x4 vv = *(const s16x4*)&miP[(size_t)rg*512 + c*64 + c4*4];
        acc[0]+=b2f((u16)vv[0]); acc[1]+=b2f((u16)vv[1]);
        acc[2]+=b2f((u16)vv[2]); acc[3]+=b2f((u16)vv[3]);
      }
      #pragma unroll
      for(int s=0;s<4;s++)
        #pragma unroll
        for(int c=0;c<8;c++){
          s16x4 vv = *(const s16x4*)&mjP[(((size_t)(s*8+z))*LL + itile*16 + row16)*512 + c*64 + c4*4];
          acc[0]+=b2f((u16)vv[0]); acc[1]+=b2f((u16)vv[1]);
          acc[2]+=b2f((u16)vv[2]); acc[3]+=b2f((u16)vv[3]);
        }
      f32x4 u0 = *(const f32x4*)&unary[(size_t)rg*64 + c4*4];
      #pragma unroll
      for(int k=0;k<4;k++) v[k] = (u0[k] + acc[k]) * mk;
    }
    if(mode == 2){
      *(f32x4*)&out[(size_t)rg*64 + c4*4] = (f32x4){v[0],v[1],v[2],v[3]};
      return;   // uniform across block: no barrier reached
    }
    // in-register row softmax: 16 lanes per row (group = c4)
    float mx = fmaxf(fmaxf(v[0],v[1]), fmaxf(v[2],v[3]));
    mx = fmaxf(mx, __shfl_xor(mx,1,64));
    mx = fmaxf(mx, __shfl_xor(mx,2,64));
    mx = fmaxf(mx, __shfl_xor(mx,4,64));
    mx = fmaxf(mx, __shfl_xor(mx,8,64));
    float s = 0.f;
    #pragma unroll
    for(int k=0;k<4;k++){ v[k] = __expf(v[k]-mx); s += v[k]; }
    s += __shfl_xor(s,1,64); s += __shfl_xor(s,2,64);
    s += __shfl_xor(s,4,64); s += __shfl_xor(s,8,64);
    float iv = mk / s;
    s16x4 q4 = { (short)f2b(v[0]*iv), (short)f2b(v[1]*iv),
                 (short)f2b(v[2]*iv), (short)f2b(v[3]*iv) };
    *(s16x4*)&qzb[(size_t)rg*64 + c4*4] = q4;
    *(s16x4*)&qlds[row16*72 + c4*4] = q4;
  }
  __syncthreads();
  // ---- P2 = rowsoftmax(qz @ gw^T), one 16x16 quadrant per wave (fixed-max exp) ----
  float fv[4];
  {
    bf16x8 a0 = ldb8(&qlds[l15*72 + lhi*8]);
    bf16x8 a1 = ldb8(&qlds[l15*72 + lhi*8 + 32]);
    const u16* Br = Gt2 + (size_t)(w*16 + l15)*64 + lhi*8;
    f32x4 acc = {0.f,0.f,0.f,0.f};
    acc = MFMA(a0, ldb8(Br), acc);
    acc = MFMA(a1, ldb8(Br+32), acc);
    #pragma unroll
    for(int jj=0;jj<4;jj++){
      float e = __expf(acc[jj]);
      fv[jj] = e;
      float p = g16_sum(e);
      if(l15==0) red2[(lhi*4+jj)*4 + w] = p;
    }
  }
  __syncthreads();
  #pragma unroll
  for(int jj=0;jj<4;jj++){
    int r = lhi*4+jj;
    float s = red2[r*4+0]+red2[r*4+1]+red2[r*4+2]+red2[r*4+3];
    float iv = 1.f/s;
    P2s[r*72 + w*16 + l15] = f2b(fv[jj]*iv);
  }
  __syncthreads();
  // ---- Mg[i,a] = sum_j P2[i,j] gw[j,a]; a-quadrant per wave ----
  {
    bf16x8 a0 = ldb8(&P2s[l15*72 + lhi*8]);
    bf16x8 a1 = ldb8(&P2s[l15*72 + lhi*8 + 32]);
    const u16* Br = Gt + (size_t)(w*16 + l15)*64 + lhi*8;
    f32x4 acc = {0.f,0.f,0.f,0.f};
    acc = MFMA(a0, ldb8(Br), acc);
    acc = MFMA(a1, ldb8(Br+32), acc);
    #pragma unroll
    for(int jj=0;jj<4;jj++)
      MgF_out[((size_t)rbase + lhi*4 + jj)*64 + w*16 + l15] = acc[jj];
  }
}

// ---- k2: per (z,c,itile): t1[i][b], t1t[b][i], t2t[a][j] — LDS-staged stores ----
__global__ __launch_bounds__(256) void k2(const u16* __restrict__ qzb,
      const u16* __restrict__ T4t, const u16* __restrict__ Tt2,
      u16* __restrict__ t1b, u16* __restrict__ t1t, u16* __restrict__ t2t){
  __shared__ u16 s1[64*72];
  __shared__ u16 s2[64*72];
  __shared__ u16 s3[64*72];
  int bid = blockIdx.x; int z = bid&7, c = (bid>>3)&7, itile = bid>>6;
  int zc = z*8 + c;
  int t = threadIdx.x, lane = t&63, w = t>>6, l15 = lane&15, lhi = lane>>4;
  int i0 = itile*64;
  const u16* qA = qzb + ((size_t)z*LL + i0 + w*16 + l15)*64 + lhi*8;
  bf16x8 qa0 = ldb8(qA), qa1 = ldb8(qA+32);
  const u16* tA = T4t + c*4096 + (w*16 + l15)*64 + lhi*8;
  bf16x8 ta0 = ldb8(tA), ta1 = ldb8(tA+32);
  const u16* uA = Tt2 + c*4096 + (w*16 + l15)*64 + lhi*8;
  bf16x8 ua0 = ldb8(uA), ua1 = ldb8(uA+32);
  #pragma unroll
  for(int nt=0;nt<4;nt++){
    {
      const u16* Br = T4t + c*4096 + (nt*16 + l15)*64 + lhi*8;
      f32x4 acc = {0.f,0.f,0.f,0.f};
      acc = MFMA(qa0, ldb8(Br), acc);
      acc = MFMA(qa1, ldb8(Br+32), acc);
      #pragma unroll
      for(int jj=0;jj<4;jj++)
        s1[(w*16 + lhi*4 + jj)*72 + nt*16 + l15] = f2b(acc[jj]);
    }
    const u16* Br = qzb + ((size_t)z*LL + i0 + nt*16 + l15)*64 + lhi*8;
    bf16x8 qb0 = ldb8(Br), qb1 = ldb8(Br+32);
    {
      f32x4 acc = {0.f,0.f,0.f,0.f};
      acc = MFMA(ta0, qb0, acc);
      acc = MFMA(ta1, qb1, acc);
      #pragma unroll
      for(int jj=0;jj<4;jj++)
        s2[(w*16 + lhi*4 + jj)*72 + nt*16 + l15] = f2b(acc[jj]);
    }
    {
      f32x4 acc = {0.f,0.f,0.f,0.f};
      acc = MFMA(ua0, qb0, acc);
      acc = MFMA(ua1, qb1, acc);
      #pragma unroll
      for(int jj=0;jj<4;jj++)
        s3[(w*16 + lhi*4 + jj)*72 + nt*16 + l15] = f2b(acc[jj]);
    }
  }
  __syncthreads();
  #pragma unroll
  for(int p=0;p<2;p++){
    int r = p*32 + (t>>3), ch = t&7;
    *(bf16x8*)&t1b[((size_t)zc*LL + i0 + r)*64 + ch*8]   = *(const bf16x8*)&s1[r*72 + ch*8];
    *(bf16x8*)&t1t[((size_t)zc*64 + r)*LL + i0 + ch*8]   = *(const bf16x8*)&s2[r*72 + ch*8];
    *(bf16x8*)&t2t[((size_t)zc*64 + r)*LL + i0 + ch*8]   = *(const bf16x8*)&s3[r*72 + ch*8];
  }
}

// ---- kF: round-9 structure + waves_per_eu(4,4) [extern-shared hid the true
// 4-waves/EU occupancy -> allocator was pinned at 64 VGPR; this unlocks 128]
// + panel-invariant qzb B-fragments hoisted + next-panel t1b prefetch. ----
__global__ __launch_bounds__(1024) __attribute__((amdgpu_waves_per_eu(4,4)))
void kF(const u16* __restrict__ t1b, const u16* __restrict__ qzb,
        const u16* __restrict__ t1t, const u16* __restrict__ t2t, const float* __restrict__ mf,
        u16* __restrict__ miP, u16* __restrict__ mjP){
  extern __shared__ char smem[];
  u16*   t2s  = (u16*)smem;                    // [64][520]   66560 B
  u16*   Pp   = (u16*)(smem + 66560);          // [32][520]   33280 B (unnormalized exp)
  u16*   PpT  = (u16*)(smem + 99840);          // [16w][32][40] 40960 B (normalized, wave-local)
  float* red  = (float*)(smem + 140800);       // [32][16]     2048 B
  float* redS = (float*)(smem + 142848);       // [32]          128 B
  float* stgf = (float*)(smem + 142976);       // [2][32][68] f32 17408 B  (end 160384)
  u16*   stg  = (u16*)smem;                    // [512][72] dump (reuses t2s+Pp, 73728 B)
  int bid = blockIdx.x;
  int z = bid&7, c = (bid>>3)&7, it = bid>>6;   // it < 4
  int zc = z*8 + c;
  int t = threadIdx.x, lane = t&63, w = t>>6, l15 = lane&15, lhi = lane>>4;
  int jc0 = w*32;                               // wave's j-slice
  int h = w>>3, wr = (w>>2)&1, wc = w&3;        // mi role
  // ---- hoisted panel-invariant qzb B-fragments (removes 4 loads/panel) ----
  bf16x8 qb00, qb01, qb10, qb11;
  {
    const u16* Br0 = qzb + ((size_t)z*LL + jc0 + l15)*64 + lhi*8;
    const u16* Br1 = qzb + ((size_t)z*LL + jc0 + 16 + l15)*64 + lhi*8;
    qb00 = ldb8(Br0); qb01 = ldb8(Br0+32);
    qb10 = ldb8(Br1); qb11 = ldb8(Br1+32);
  }
  // ---- prefetch panel 0 A-fragments ----
  bf16x8 pa0[2], pa1[2];
  #pragma unroll
  for(int rt=0;rt<2;rt++){
    const u16* Ar = t1b + ((size_t)zc*LL + it*128 + rt*16 + l15)*64 + lhi*8;
    pa0[rt] = ldb8(Ar); pa1[rt] = ldb8(Ar+32);
  }
  #pragma unroll
  for(int m=0;m<4;m++){
    int e = (m*1024 + t)*8;
    int a = e >> 9, j = e & 511;
    *(bf16x8*)&t2s[a*520 + j] = ldb8(t2t + ((size_t)zc*64 + a)*LL + j);
  }
  float mfj[2];
  mfj[0] = mf[z*LL + jc0 + l15];
  mfj[1] = mf[z*LL + jc0 + 16 + l15];
  f32x4 mj[2][4];
  #pragma unroll
  for(int jt=0;jt<2;jt++)
    #pragma unroll
    for(int bt=0;bt<4;bt++) mj[jt][bt] = (f32x4){0.f,0.f,0.f,0.f};
  u16* PpTw = PpT + w*32*40;                    // wave-local transpose buffer

  for(int ip=0; ip<4; ++ip){
    int i0g = it*128 + ip*32;
    f32x4 S[2][2];
    #pragma unroll
    for(int rt=0;rt<2;rt++){ S[rt][0] = (f32x4){0,0,0,0}; S[rt][1] = (f32x4){0,0,0,0}; }
    #pragma unroll
    for(int rt=0;rt<2;rt++){
      S[rt][0] = MFMA(pa0[rt], qb00, S[rt][0]);
      S[rt][0] = MFMA(pa1[rt], qb01, S[rt][0]);
      S[rt][1] = MFMA(pa0[rt], qb10, S[rt][1]);
      S[rt][1] = MFMA(pa1[rt], qb11, S[rt][1]);
    }
    // ---- prefetch next panel's A-fragments (hides t1b latency under exp/mi) ----
    {
      int ipn = (ip < 3) ? ip + 1 : ip;
      int i0n = it*128 + ipn*32;
      #pragma unroll
      for(int rt=0;rt<2;rt++){
        const u16* Ar = t1b + ((size_t)zc*LL + i0n + rt*16 + l15)*64 + lhi*8;
        pa0[rt] = ldb8(Ar); pa1[rt] = ldb8(Ar+32);
      }
    }
    #pragma unroll
    for(int rt=0;rt<2;rt++)
      #pragma unroll
      for(int jj=0;jj<4;jj++){
        int rloc = rt*16 + lhi*4 + jj;
        int irow = i0g + rloc;
        float mfi = mf[z*LL + irow];
        float ps = 0.f;
        #pragma unroll
        for(int ct=0;ct<2;ct++){
          int jcol = jc0 + ct*16 + l15;
          float v = S[rt][ct][jj] - ((irow==jcol)?BIGV:0.f);
          float e = mfi * mfj[ct] * __expf(v);
          S[rt][ct][jj] = e; ps += e;
          Pp[rloc*520 + jcol] = f2b(e);        // unnormalized
        }
        ps = g16_sum(ps);
        if(l15 == 0) red[rloc*16 + w] = ps;
      }
    __syncthreads();                            // B1: Pp/red (and t2s, ip=0) ready
    if(t < 512){
      float v = red[t];
      v += __shfl_xor(v,1,64); v += __shfl_xor(v,2,64);
      v += __shfl_xor(v,4,64); v += __shfl_xor(v,8,64);
      if((t&15)==0) redS[t>>4] = v;
    }
    __syncthreads();                            // B1.5: redS ready
    float ivv[2][4];
    #pragma unroll
    for(int rt=0;rt<2;rt++)
      #pragma unroll
      for(int jj=0;jj<4;jj++){
        float s = redS[rt*16 + lhi*4 + jj];
        ivv[rt][jj] = s > 0.f ? 1.f/s : 0.f;
      }
    #pragma unroll
    for(int rt=0;rt<2;rt++)
      #pragma unroll
      for(int ct=0;ct<2;ct++){
        s16x4 v4 = { (short)f2b(S[rt][ct][0]*ivv[rt][0]), (short)f2b(S[rt][ct][1]*ivv[rt][1]),
                     (short)f2b(S[rt][ct][2]*ivv[rt][2]), (short)f2b(S[rt][ct][3]*ivv[rt][3]) };
        *(s16x4*)&PpTw[(ct*16 + l15)*40 + rt*16 + lhi*4] = v4;
      }
    {
      f32x4 mia = {0.f,0.f,0.f,0.f};
      const u16* Ab = Pp + (wr*16 + l15)*520 + h*256 + lhi*8;
      const u16* Bb = t2s + (wc*16 + l15)*520 + h*256 + lhi*8;
      #pragma unroll
      for(int ks=0;ks<8;ks++)
        mia = MFMA(ldb8(Ab + ks*32), ldb8(Bb + ks*32), mia);
      #pragma unroll
      for(int jj=0;jj<4;jj++)
        stgf[(h*32 + wr*16 + lhi*4 + jj)*68 + wc*16 + l15] = mia[jj]*ivv[wr][jj];
    }
    {
      bf16x8 av[2];
      #pragma unroll
      for(int jt=0;jt<2;jt++)
        av[jt] = ldb8(PpTw + (jt*16 + l15)*40 + lhi*8);
      #pragma unroll
      for(int bt=0;bt<4;bt++){
        bf16x8 b = ldb8(t1t + ((size_t)zc*64 + bt*16 + l15)*LL + i0g + lhi*8);
        #pragma unroll
        for(int jt=0;jt<2;jt++) mj[jt][bt] = MFMA(av[jt], b, mj[jt][bt]);
      }
    }
    __syncthreads();                            // B2: stgf ready; Pp/red/t2s reads done
    if(t < 512){
      int r = t>>4, cc = t&15;
      f32x4 v0 = *(const f32x4*)&stgf[r*68 + cc*4];
      f32x4 v1 = *(const f32x4*)&stgf[(32+r)*68 + cc*4];
      s16x4 o = { (short)f2b(v0[0]+v1[0]), (short)f2b(v0[1]+v1[1]),
                  (short)f2b(v0[2]+v1[2]), (short)f2b(v0[3]+v1[3]) };
      *(s16x4*)&miP[((size_t)z*LL + i0g + r)*512 + c*64 + cc*4] = o;
    }
  }
  #pragma unroll
  for(int jt=0;jt<2;jt++)
    #pragma unroll
    for(int bt=0;bt<4;bt++)
      #pragma unroll
      for(int jj=0;jj<4;jj++)
        stg[(jc0 + jt*16 + lhi*4 + jj)*72 + bt*16 + l15] = f2b(mj[jt][bt][jj]);
  __syncthreads();
  #pragma unroll
  for(int q=0;q<4;q++){
    int e = q*1024 + t;
    int j = e >> 3, ch = e & 7;
    *(bf16x8*)&mjP[(((size_t)(it*8 + z))*LL + j)*512 + c*64 + ch*8]
      = *(const bf16x8*)&stg[j*72 + ch*8];
  }
}

extern "C" void kernel_launch(void* const* d_in, const int* in_sizes, int n_in,
                              void* d_out, int out_size, void* d_ws, size_t ws_size,
                              hipStream_t stream) {
  const float* x       = (const float*)d_in[0];
  const int*   mask    = (const int*)d_in[1];
  const float* ternary = (const float*)d_in[2];
  const float* gw      = (const float*)d_in[3];
  float* out = (float*)d_out;

  const size_t NE = (size_t)BB*LL*64;          // 262144
  char* p = (char*)d_ws;
  auto alloc = [&](size_t bytes)->void*{
    void* r = (void*)p; p += (bytes + 255) & ~(size_t)255; return r;
  };
  float* unary   = (float*)alloc(NE*4);
  float* mf      = (float*)alloc((size_t)BB*LL*4);
  u16*   qzb     = (u16*)alloc(NE*2);
  u16*   t1b     = (u16*)alloc((size_t)BB*HH*LL*64*2);   // 4.2 MB
  u16*   t1t     = (u16*)alloc((size_t)BB*HH*LL*64*2);   // 4.2 MB
  u16*   t2t     = (u16*)alloc((size_t)BB*HH*LL*64*2);   // 4.2 MB
  float* MgF     = (float*)alloc(NE*4);                  // 1 MB
  u16*   miP     = (u16*)alloc((size_t)BB*LL*512*2);     // 4.2 MB
  u16*   mjP     = (u16*)alloc((size_t)32*LL*512*2);     // 16.8 MB (4 it-partials)
  u16*   T4t     = (u16*)alloc(32768*2);
  u16*   Tt2     = (u16*)alloc(32768*2);
  u16*   Gt      = (u16*)alloc(4096*2);
  u16*   Gt2     = (u16*)alloc(4096*2);

  const int KF_LDS = 160384;  // t2s + Pp + PpT + red + redS + stgf
  hipFuncSetAttribute(reinterpret_cast<const void*>(kF),
                      hipFuncAttributeMaxDynamicSharedMemorySize, KF_LDS);

  kp_prep<<<128, 256, 0, stream>>>(ternary, gw, T4t, Tt2, Gt, Gt2);
  kCA<<<256, 256, 0, stream>>>(x, mask, miP, mjP, MgF, unary, mf, Gt2, Gt,
                               qzb, MgF, out, 0);
  for(int it=0; it<4; ++it){
    k2<<<512, 256, 0, stream>>>(qzb, T4t, Tt2, t1b, t1t, t2t);
    kF<<<256, 1024, KF_LDS, stream>>>(t1b, qzb, t1t, t2t, mf, miP, mjP);
    kCA<<<256, 256, 0, stream>>>(x, mask, miP, mjP, MgF, unary, mf, Gt2, Gt,
                                 qzb, MgF, out, (it==3) ? 2 : 1);
  }
}

// Round 15
// 220.279 us; speedup vs baseline: 1.5001x; 1.5001x over previous
//
#include <hip/hip_runtime.h>

#define BB 8
#define LL 512
#define HH 8
#define BIGV (1e9f)

typedef unsigned short u16;
typedef __attribute__((ext_vector_type(8))) short bf16x8;
typedef __attribute__((ext_vector_type(4))) short s16x4;
typedef __attribute__((ext_vector_type(4))) float f32x4;

#define MFMA(a,b,c) __builtin_amdgcn_mfma_f32_16x16x32_bf16(a,b,c,0,0,0)

__device__ __forceinline__ u16 f2b(float f){
  unsigned u = __float_as_uint(f);
  u = (u + 0x7fffu + ((u>>16)&1u)) >> 16;
  return (u16)u;
}
__device__ __forceinline__ float b2f(u16 s){ return __uint_as_float(((unsigned)s)<<16); }
__device__ __forceinline__ bf16x8 ldb8(const u16* p){ return *(const bf16x8*)p; }

__device__ __forceinline__ float g16_sum(float v){
  v += __shfl_xor(v,1,64); v += __shfl_xor(v,2,64);
  v += __shfl_xor(v,4,64); v += __shfl_xor(v,8,64);
  return v;
}

// ---- tables: T4t[c][b][a], Tt2[c][a][b], Gt[a][j], Gt2[j][a] ----
__global__ void kp_prep(const float* __restrict__ T, const float* __restrict__ gw,
                        u16* __restrict__ T4t, u16* __restrict__ Tt2,
                        u16* __restrict__ Gt, u16* __restrict__ Gt2){
  int idx = blockIdx.x*256 + threadIdx.x;   // < 32768
  { int c=idx>>12, b=(idx>>6)&63, a=idx&63; T4t[idx] = f2b(T[(a*64+b)*8+c]); }
  { int c=idx>>12, a=(idx>>6)&63, b=idx&63; Tt2[idx] = f2b(T[(a*64+b)*8+c]); }
  if(idx < 4096){
    int a=idx>>6, j=idx&63;
    Gt[idx]  = f2b(gw[j*64+a]);   // Gt[a][j]
    Gt2[idx] = f2b(gw[idx]);      // Gt2[j][a]
  }
}

// ---- kCA: fused [new_qz] + [row softmax in-register] + [P2/Mg MFMA] ----
__global__ __launch_bounds__(256) void kCA(const float* __restrict__ x, const int* __restrict__ mask,
      const u16* __restrict__ miP, const u16* __restrict__ mjP, const float* __restrict__ MgF_in,
      float* __restrict__ unary, float* __restrict__ mf,
      const u16* __restrict__ Gt2, const u16* __restrict__ Gt,
      u16* __restrict__ qzb, float* __restrict__ MgF_out, float* __restrict__ out, int mode){
  __shared__ u16 qlds[16*72];
  __shared__ u16 P2s[16*72];
  __shared__ float red2[16*4];
  int bid = blockIdx.x; int z = bid & 7, itile = bid >> 3;   // z-affine for XCD L2
  int t = threadIdx.x, lane = t&63, w = t>>6, l15 = lane&15, lhi = lane>>4;
  int rbase = z*LL + itile*16;
  {
    int row16 = t>>4, c4 = t&15;
    int rg = rbase + row16;
    float v[4]; float mk;
    if(mode == 0){
      mk = (mask[rg] != 0) ? 1.f : 0.f;
      if(c4 == 0) mf[rg] = mk;
      int pos = rg & (LL-1);
      #pragma unroll
      for(int k=0;k<4;k++){
        int d = c4*4 + k;
        float div = __expf(-(float)(d & ~1) * 0.14391156962f);  // ln(10000)/64
        float arg = (float)pos * div;
        float pe = (d & 1) ? cosf(arg) : sinf(arg);
        v[k] = (x[(size_t)rg*64 + d] + pe) * mk;
      }
      *(f32x4*)&unary[(size_t)rg*64 + c4*4] = (f32x4){v[0],v[1],v[2],v[3]};
    } else {
      mk = mf[rg];
      f32x4 acc = *(const f32x4*)&MgF_in[(size_t)rg*64 + c4*4];
      #pragma unroll
      for(int c=0;c<8;c++){
        s16x4 vv = *(const s16x4*)&miP[(size_t)rg*512 + c*64 + c4*4];
        acc[0]+=b2f((u16)vv[0]); acc[1]+=b2f((u16)vv[1]);
        acc[2]+=b2f((u16)vv[2]); acc[3]+=b2f((u16)vv[3]);
      }
      #pragma unroll
      for(int s=0;s<4;s++)
        #pragma unroll
        for(int c=0;c<8;c++){
          s16x4 vv = *(const s16x4*)&mjP[(((size_t)(s*8+z))*LL + itile*16 + row16)*512 + c*64 + c4*4];
          acc[0]+=b2f((u16)vv[0]); acc[1]+=b2f((u16)vv[1]);
          acc[2]+=b2f((u16)vv[2]); acc[3]+=b2f((u16)vv[3]);
        }
      f32x4 u0 = *(const f32x4*)&unary[(size_t)rg*64 + c4*4];
      #pragma unroll
      for(int k=0;k<4;k++) v[k] = (u0[k] + acc[k]) * mk;
    }
    if(mode == 2){
      *(f32x4*)&out[(size_t)rg*64 + c4*4] = (f32x4){v[0],v[1],v[2],v[3]};
      return;   // uniform across block: no barrier reached
    }
    // in-register row softmax: 16 lanes per row (group = c4)
    float mx = fmaxf(fmaxf(v[0],v[1]), fmaxf(v[2],v[3]));
    mx = fmaxf(mx, __shfl_xor(mx,1,64));
    mx = fmaxf(mx, __shfl_xor(mx,2,64));
    mx = fmaxf(mx, __shfl_xor(mx,4,64));
    mx = fmaxf(mx, __shfl_xor(mx,8,64));
    float s = 0.f;
    #pragma unroll
    for(int k=0;k<4;k++){ v[k] = __expf(v[k]-mx); s += v[k]; }
    s += __shfl_xor(s,1,64); s += __shfl_xor(s,2,64);
    s += __shfl_xor(s,4,64); s += __shfl_xor(s,8,64);
    float iv = mk / s;
    s16x4 q4 = { (short)f2b(v[0]*iv), (short)f2b(v[1]*iv),
                 (short)f2b(v[2]*iv), (short)f2b(v[3]*iv) };
    *(s16x4*)&qzb[(size_t)rg*64 + c4*4] = q4;
    *(s16x4*)&qlds[row16*72 + c4*4] = q4;
  }
  __syncthreads();
  // ---- P2 = rowsoftmax(qz @ gw^T), one 16x16 quadrant per wave (fixed-max exp) ----
  float fv[4];
  {
    bf16x8 a0 = ldb8(&qlds[l15*72 + lhi*8]);
    bf16x8 a1 = ldb8(&qlds[l15*72 + lhi*8 + 32]);
    const u16* Br = Gt2 + (size_t)(w*16 + l15)*64 + lhi*8;
    f32x4 acc = {0.f,0.f,0.f,0.f};
    acc = MFMA(a0, ldb8(Br), acc);
    acc = MFMA(a1, ldb8(Br+32), acc);
    #pragma unroll
    for(int jj=0;jj<4;jj++){
      float e = __expf(acc[jj]);
      fv[jj] = e;
      float p = g16_sum(e);
      if(l15==0) red2[(lhi*4+jj)*4 + w] = p;
    }
  }
  __syncthreads();
  #pragma unroll
  for(int jj=0;jj<4;jj++){
    int r = lhi*4+jj;
    float s = red2[r*4+0]+red2[r*4+1]+red2[r*4+2]+red2[r*4+3];
    float iv = 1.f/s;
    P2s[r*72 + w*16 + l15] = f2b(fv[jj]*iv);
  }
  __syncthreads();
  // ---- Mg[i,a] = sum_j P2[i,j] gw[j,a]; a-quadrant per wave ----
  {
    bf16x8 a0 = ldb8(&P2s[l15*72 + lhi*8]);
    bf16x8 a1 = ldb8(&P2s[l15*72 + lhi*8 + 32]);
    const u16* Br = Gt + (size_t)(w*16 + l15)*64 + lhi*8;
    f32x4 acc = {0.f,0.f,0.f,0.f};
    acc = MFMA(a0, ldb8(Br), acc);
    acc = MFMA(a1, ldb8(Br+32), acc);
    #pragma unroll
    for(int jj=0;jj<4;jj++)
      MgF_out[((size_t)rbase + lhi*4 + jj)*64 + w*16 + l15] = acc[jj];
  }
}

// ---- k2: per (z,c,itile): t1[i][b], t1t[b][i], t2t[a][j] — LDS-staged stores ----
__global__ __launch_bounds__(256) void k2(const u16* __restrict__ qzb,
      const u16* __restrict__ T4t, const u16* __restrict__ Tt2,
      u16* __restrict__ t1b, u16* __restrict__ t1t, u16* __restrict__ t2t){
  __shared__ u16 s1[64*72];
  __shared__ u16 s2[64*72];
  __shared__ u16 s3[64*72];
  int bid = blockIdx.x; int z = bid&7, c = (bid>>3)&7, itile = bid>>6;
  int zc = z*8 + c;
  int t = threadIdx.x, lane = t&63, w = t>>6, l15 = lane&15, lhi = lane>>4;
  int i0 = itile*64;
  const u16* qA = qzb + ((size_t)z*LL + i0 + w*16 + l15)*64 + lhi*8;
  bf16x8 qa0 = ldb8(qA), qa1 = ldb8(qA+32);
  const u16* tA = T4t + c*4096 + (w*16 + l15)*64 + lhi*8;
  bf16x8 ta0 = ldb8(tA), ta1 = ldb8(tA+32);
  const u16* uA = Tt2 + c*4096 + (w*16 + l15)*64 + lhi*8;
  bf16x8 ua0 = ldb8(uA), ua1 = ldb8(uA+32);
  #pragma unroll
  for(int nt=0;nt<4;nt++){
    {
      const u16* Br = T4t + c*4096 + (nt*16 + l15)*64 + lhi*8;
      f32x4 acc = {0.f,0.f,0.f,0.f};
      acc = MFMA(qa0, ldb8(Br), acc);
      acc = MFMA(qa1, ldb8(Br+32), acc);
      #pragma unroll
      for(int jj=0;jj<4;jj++)
        s1[(w*16 + lhi*4 + jj)*72 + nt*16 + l15] = f2b(acc[jj]);
    }
    const u16* Br = qzb + ((size_t)z*LL + i0 + nt*16 + l15)*64 + lhi*8;
    bf16x8 qb0 = ldb8(Br), qb1 = ldb8(Br+32);
    {
      f32x4 acc = {0.f,0.f,0.f,0.f};
      acc = MFMA(ta0, qb0, acc);
      acc = MFMA(ta1, qb1, acc);
      #pragma unroll
      for(int jj=0;jj<4;jj++)
        s2[(w*16 + lhi*4 + jj)*72 + nt*16 + l15] = f2b(acc[jj]);
    }
    {
      f32x4 acc = {0.f,0.f,0.f,0.f};
      acc = MFMA(ua0, qb0, acc);
      acc = MFMA(ua1, qb1, acc);
      #pragma unroll
      for(int jj=0;jj<4;jj++)
        s3[(w*16 + lhi*4 + jj)*72 + nt*16 + l15] = f2b(acc[jj]);
    }
  }
  __syncthreads();
  #pragma unroll
  for(int p=0;p<2;p++){
    int r = p*32 + (t>>3), ch = t&7;
    *(bf16x8*)&t1b[((size_t)zc*LL + i0 + r)*64 + ch*8]   = *(const bf16x8*)&s1[r*72 + ch*8];
    *(bf16x8*)&t1t[((size_t)zc*64 + r)*LL + i0 + ch*8]   = *(const bf16x8*)&s2[r*72 + ch*8];
    *(bf16x8*)&t2t[((size_t)zc*64 + r)*LL + i0 + ch*8]   = *(const bf16x8*)&s3[r*72 + ch*8];
  }
}

// ---- kF: round-13 structure; two-stage red/redS reduce replaced by LDS
// atomic f32 adds into parity-double-buffered redS2 -> B1.5 + reduce deleted
// (3 fewer barriers/block). No new persistent VGPR state (64-VGPR pin stands).
__global__ __launch_bounds__(1024) void kF(const u16* __restrict__ t1b, const u16* __restrict__ qzb,
        const u16* __restrict__ t1t, const u16* __restrict__ t2t, const float* __restrict__ mf,
        u16* __restrict__ miP, u16* __restrict__ mjP){
  extern __shared__ char smem[];
  u16*   t2s  = (u16*)smem;                    // [64][520]   66560 B
  u16*   Pp   = (u16*)(smem + 66560);          // [32][520]   33280 B (unnormalized exp)
  u16*   PpT  = (u16*)(smem + 99840);          // [16w][32][40] 40960 B (normalized, wave-local)
  float* redS2= (float*)(smem + 140800);       // [2][32]      256 B (parity row-sums)
  float* stgf = (float*)(smem + 141056);       // [2][32][68] f32 17408 B  (end 158464)
  u16*   stg  = (u16*)smem;                    // [512][72] dump (reuses t2s+Pp, 73728 B)
  int bid = blockIdx.x;
  int z = bid&7, c = (bid>>3)&7, it = bid>>6;   // it < 4
  int zc = z*8 + c;
  int t = threadIdx.x, lane = t&63, w = t>>6, l15 = lane&15, lhi = lane>>4;
  int jc0 = w*32;                               // wave's j-slice
  int h = w>>3, wr = (w>>2)&1, wc = w&3;        // mi role
  // ---- zero both parity sum buffers; barrier BEFORE any global load so the
  // implicit waitcnt drain is empty ----
  if(t < 64) redS2[t] = 0.f;
  __syncthreads();
  #pragma unroll
  for(int m=0;m<4;m++){
    int e = (m*1024 + t)*8;
    int a = e >> 9, j = e & 511;
    *(bf16x8*)&t2s[a*520 + j] = ldb8(t2t + ((size_t)zc*64 + a)*LL + j);
  }
  float mfj[2];
  mfj[0] = mf[z*LL + jc0 + l15];
  mfj[1] = mf[z*LL + jc0 + 16 + l15];
  f32x4 mj[2][4];
  #pragma unroll
  for(int jt=0;jt<2;jt++)
    #pragma unroll
    for(int bt=0;bt<4;bt++) mj[jt][bt] = (f32x4){0.f,0.f,0.f,0.f};
  u16* PpTw = PpT + w*32*40;                    // wave-local transpose buffer

  for(int ip=0; ip<4; ++ip){
    int i0g = it*128 + ip*32;
    int par = ip & 1;
    f32x4 S[2][2];
    #pragma unroll
    for(int rt=0;rt<2;rt++){ S[rt][0] = (f32x4){0,0,0,0}; S[rt][1] = (f32x4){0,0,0,0}; }
    #pragma unroll
    for(int rt=0;rt<2;rt++){
      const u16* Ar = t1b + ((size_t)zc*LL + i0g + rt*16 + l15)*64 + lhi*8;
      bf16x8 a0 = ldb8(Ar), a1 = ldb8(Ar+32);
      #pragma unroll
      for(int ct=0;ct<2;ct++){
        const u16* Br = qzb + ((size_t)z*LL + jc0 + ct*16 + l15)*64 + lhi*8;
        S[rt][ct] = MFMA(a0, ldb8(Br), S[rt][ct]);
        S[rt][ct] = MFMA(a1, ldb8(Br+32), S[rt][ct]);
      }
    }
    // ---- mask/diag/exp (fixed max), atomic row-sums, unnormalized Pp ----
    #pragma unroll
    for(int rt=0;rt<2;rt++)
      #pragma unroll
      for(int jj=0;jj<4;jj++){
        int rloc = rt*16 + lhi*4 + jj;
        int irow = i0g + rloc;
        float mfi = mf[z*LL + irow];
        float ps = 0.f;
        #pragma unroll
        for(int ct=0;ct<2;ct++){
          int jcol = jc0 + ct*16 + l15;
          float v = S[rt][ct][jj] - ((irow==jcol)?BIGV:0.f);
          float e = mfi * mfj[ct] * __expf(v);
          S[rt][ct][jj] = e; ps += e;
          Pp[rloc*520 + jcol] = f2b(e);        // unnormalized
        }
        ps = g16_sum(ps);
        if(l15 == 0) atomicAdd(&redS2[par*32 + rloc], ps);   // ds_add_f32, no-return
      }
    __syncthreads();                            // B1: Pp + redS2[par] complete (t2s on ip=0)
    if(t < 32) redS2[(par^1)*32 + t] = 0.f;     // zero other parity for next panel
    float ivv[2][4];
    #pragma unroll
    for(int rt=0;rt<2;rt++)
      #pragma unroll
      for(int jj=0;jj<4;jj++){
        float s = redS2[par*32 + rt*16 + lhi*4 + jj];
        ivv[rt][jj] = s > 0.f ? 1.f/s : 0.f;
      }
    #pragma unroll
    for(int rt=0;rt<2;rt++)
      #pragma unroll
      for(int ct=0;ct<2;ct++){
        s16x4 v4 = { (short)f2b(S[rt][ct][0]*ivv[rt][0]), (short)f2b(S[rt][ct][1]*ivv[rt][1]),
                     (short)f2b(S[rt][ct][2]*ivv[rt][2]), (short)f2b(S[rt][ct][3]*ivv[rt][3]) };
        *(s16x4*)&PpTw[(ct*16 + l15)*40 + rt*16 + lhi*4] = v4;
      }
    {
      f32x4 mia = {0.f,0.f,0.f,0.f};
      const u16* Ab = Pp + (wr*16 + l15)*520 + h*256 + lhi*8;
      const u16* Bb = t2s + (wc*16 + l15)*520 + h*256 + lhi*8;
      #pragma unroll
      for(int ks=0;ks<8;ks++)
        mia = MFMA(ldb8(Ab + ks*32), ldb8(Bb + ks*32), mia);
      #pragma unroll
      for(int jj=0;jj<4;jj++)
        stgf[(h*32 + wr*16 + lhi*4 + jj)*68 + wc*16 + l15] = mia[jj]*ivv[wr][jj];
    }
    {
      bf16x8 av[2];
      #pragma unroll
      for(int jt=0;jt<2;jt++)
        av[jt] = ldb8(PpTw + (jt*16 + l15)*40 + lhi*8);
      #pragma unroll
      for(int bt=0;bt<4;bt++){
        bf16x8 b = ldb8(t1t + ((size_t)zc*64 + bt*16 + l15)*LL + i0g + lhi*8);
        #pragma unroll
        for(int jt=0;jt<2;jt++) mj[jt][bt] = MFMA(av[jt], b, mj[jt][bt]);
      }
    }
    __syncthreads();                            // B2: stgf ready; Pp/t2s reads done;
                                                //     orders parity-zero vs next atomics
    if(t < 512){
      int r = t>>4, cc = t&15;
      f32x4 v0 = *(const f32x4*)&stgf[r*68 + cc*4];
      f32x4 v1 = *(const f32x4*)&stgf[(32+r)*68 + cc*4];
      s16x4 o = { (short)f2b(v0[0]+v1[0]), (short)f2b(v0[1]+v1[1]),
                  (short)f2b(v0[2]+v1[2]), (short)f2b(v0[3]+v1[3]) };
      *(s16x4*)&miP[((size_t)z*LL + i0g + r)*512 + c*64 + cc*4] = o;
    }
  }
  // ---- mj dump: single pass, stg[512][72] reuses dead t2s+Pp space ----
  #pragma unroll
  for(int jt=0;jt<2;jt++)
    #pragma unroll
    for(int bt=0;bt<4;bt++)
      #pragma unroll
      for(int jj=0;jj<4;jj++)
        stg[(jc0 + jt*16 + lhi*4 + jj)*72 + bt*16 + l15] = f2b(mj[jt][bt][jj]);
  __syncthreads();
  #pragma unroll
  for(int q=0;q<4;q++){
    int e = q*1024 + t;
    int j = e >> 3, ch = e & 7;
    *(bf16x8*)&mjP[(((size_t)(it*8 + z))*LL + j)*512 + c*64 + ch*8]
      = *(const bf16x8*)&stg[j*72 + ch*8];
  }
}

extern "C" void kernel_launch(void* const* d_in, const int* in_sizes, int n_in,
                              void* d_out, int out_size, void* d_ws, size_t ws_size,
                              hipStream_t stream) {
  const float* x       = (const float*)d_in[0];
  const int*   mask    = (const int*)d_in[1];
  const float* ternary = (const float*)d_in[2];
  const float* gw      = (const float*)d_in[3];
  float* out = (float*)d_out;

  const size_t NE = (size_t)BB*LL*64;          // 262144
  char* p = (char*)d_ws;
  auto alloc = [&](size_t bytes)->void*{
    void* r = (void*)p; p += (bytes + 255) & ~(size_t)255; return r;
  };
  float* unary   = (float*)alloc(NE*4);
  float* mf      = (float*)alloc((size_t)BB*LL*4);
  u16*   qzb     = (u16*)alloc(NE*2);
  u16*   t1b     = (u16*)alloc((size_t)BB*HH*LL*64*2);   // 4.2 MB
  u16*   t1t     = (u16*)alloc((size_t)BB*HH*LL*64*2);   // 4.2 MB
  u16*   t2t     = (u16*)alloc((size_t)BB*HH*LL*64*2);   // 4.2 MB
  float* MgF     = (float*)alloc(NE*4);                  // 1 MB
  u16*   miP     = (u16*)alloc((size_t)BB*LL*512*2);     // 4.2 MB
  u16*   mjP     = (u16*)alloc((size_t)32*LL*512*2);     // 16.8 MB (4 it-partials)
  u16*   T4t     = (u16*)alloc(32768*2);
  u16*   Tt2     = (u16*)alloc(32768*2);
  u16*   Gt      = (u16*)alloc(4096*2);
  u16*   Gt2     = (u16*)alloc(4096*2);

  const int KF_LDS = 158464;  // t2s + Pp + PpT + redS2 + stgf
  hipFuncSetAttribute(reinterpret_cast<const void*>(kF),
                      hipFuncAttributeMaxDynamicSharedMemorySize, KF_LDS);

  kp_prep<<<128, 256, 0, stream>>>(ternary, gw, T4t, Tt2, Gt, Gt2);
  kCA<<<256, 256, 0, stream>>>(x, mask, miP, mjP, MgF, unary, mf, Gt2, Gt,
                               qzb, MgF, out, 0);
  for(int it=0; it<4; ++it){
    k2<<<512, 256, 0, stream>>>(qzb, T4t, Tt2, t1b, t1t, t2t);
    kF<<<256, 1024, KF_LDS, stream>>>(t1b, qzb, t1t, t2t, mf, miP, mjP);
    kCA<<<256, 256, 0, stream>>>(x, mask, miP, mjP, MgF, unary, mf, Gt2, Gt,
                                 qzb, MgF, out, (it==3) ? 2 : 1);
  }
}